// Round 7
// baseline (148.303 us; speedup 1.0000x reference)
//
#include <hip/hip_runtime.h>
#include <stdint.h>

// Problem constants: B=32, H=512, W=512, P=100000
#define W_        512
#define HWIMG     (512 * 512)
#define P_        100000
#define B_        32
#define NTOT      3200000
#define NBLK_CONV 1024
#define KG_THREADS 512
#define CHUNK     4096                 // points per gather block (512 thr * 8)
#define NCHUNK    25                   // 25*4096 = 102400 >= P_
#define NBLK_G    (B_ * NCHUNK)        // 800
#define NPT       4096                 // points per block (= CHUNK)
#define NBAND     64                   // 4 KB image bands (8 rows of int8)

typedef int   iv4 __attribute__((ext_vector_type(4)));
typedef float fv4 __attribute__((ext_vector_type(4)));

// ---- linear int8 quantization (R12-proven) ---------------------------------
__device__ __forceinline__ unsigned enc8(float z) {
    int q = __float2int_rn(fmaf(z, 32.0f, 128.0f));
    q = q < 0 ? 0 : (q > 255 ? 255 : q);
    return (unsigned)q;
}
__device__ __forceinline__ float dec8(unsigned q) {
    return fmaf((float)q, 0.03125f, -4.0f);
}

// ============ kernel 1: image fp32 -> int8 convert ==========================
// XCD-aligned batch mapping so each XCD's L2 keeps its 4 batches' int8 images
// (1 MB/XCD) dirty-resident for kernel 2's gathers (same mapping).
__global__ __launch_bounds__(256) void kConv(
    const float* __restrict__ img,
    unsigned* __restrict__ bimg_u32,
    float* __restrict__ out)
{
    const int t = threadIdx.x;
    if (blockIdx.x == 0 && t == 0) out[0] = 0.0f;
    const int b0    = blockIdx.x;
    const int batch = ((b0 & 7) << 2) | ((b0 >> 3) & 3);   // XCD-aligned
    const int inner = b0 >> 5;                             // 0..31
    const fv4* src = (const fv4*)img + (size_t)batch * 65536 + inner * 2048;
    unsigned*  dst = bimg_u32 + (size_t)batch * 65536 + inner * 2048;
#pragma unroll
    for (int ii = 0; ii < 8; ++ii) {
        const int idx = ii * 256 + t;
        const fv4 f = __builtin_nontemporal_load(src + idx);
        dst[idx] = enc8(f.x) | (enc8(f.y) << 8) | (enc8(f.z) << 16) | (enc8(f.w) << 24);
    }
}

// ============ kernel 2: A-sorted gather + fused loss ========================
// Per block: 4096 points. Only the A-gather is counting-sorted by 4 KB band
// (4096 tasks, half of R4's 8192); B's packed (addr<<2)|ord lives in a plain
// pid-indexed LDS array written coalesced. The gather loop owns whole points:
// sorted A-gather + bo[pid] LDS lookup + B-gather + loss computed inline.
// Drops res[] + readback phase + half the sort machinery; LDS 41.5 -> 33.3 KB
// -> 4 blocks/CU (32 waves vs 24) so blocks overlap each other's phases.
// Invalid tail points encode (A=0, B=0, ord=1) -> d=0, mask=0 -> loss 0.
__global__ __launch_bounds__(KG_THREADS) void kG(
    const unsigned char* __restrict__ bimg,
    const int* __restrict__ xA, const int* __restrict__ yA,
    const int* __restrict__ xB, const int* __restrict__ yB,
    const int* __restrict__ ordn,
    float* __restrict__ out)
{
    __shared__ __align__(16) unsigned taskA[NPT];      // 16 KB: (Aaddr<<12)|pid
    __shared__ __align__(16) unsigned bo[NPT];         // 16 KB: (Baddr<<2)|ord
    __shared__ unsigned hist[NBAND];
    __shared__ unsigned pfx[NBAND];
    __shared__ float ws[KG_THREADS / 64];

    const int t     = threadIdx.x;
    const int lb    = blockIdx.x;                          // 0..799
    const int batch = ((lb & 7) << 2) | ((lb >> 3) & 3);   // XCD-aligned (matches kConv)
    const int base  = (lb >> 5) * CHUNK;                   // chunk 0..24
    const unsigned char* imb = bimg + (size_t)batch * HWIMG;

    if (t < NBAND) hist[t] = 0;
    __syncthreads();

    // ---- phase 1: issue ALL index loads first (10 dwordx4 in flight) -------
    iv4 xa[2], ya[2], xb[2], yb[2], od[2];
    bool okk[2];
#pragma unroll
    for (int k = 0; k < 2; ++k) {
        const int pl = base + k * 2048 + t * 4;
        okk[k] = pl < P_;                                  // P_%4==0 -> whole iv4 valid
        const int gi = batch * P_ + (okk[k] ? pl : 0);
        xa[k] = __builtin_nontemporal_load((const iv4*)(xA + gi));
        ya[k] = __builtin_nontemporal_load((const iv4*)(yA + gi));
        xb[k] = __builtin_nontemporal_load((const iv4*)(xB + gi));
        yb[k] = __builtin_nontemporal_load((const iv4*)(yB + gi));
        od[k] = __builtin_nontemporal_load((const iv4*)(ordn + gi));
    }

    // ---- phase 2: build A-addrs, write bo coalesced (b128), hist atomics ---
    unsigned aaddr[8], rk[8];
#pragma unroll
    for (int k = 0; k < 2; ++k) {
        uint4 bop;
#pragma unroll
        for (int j = 0; j < 4; ++j) {
            const int idx = k * 4 + j;
            const bool ok = okk[k];
            const unsigned A  = ok ? (((unsigned)ya[k][j] << 9) | (unsigned)xa[k][j]) : 0u;
            const unsigned Bv = ok ? (((unsigned)yb[k][j] << 9) | (unsigned)xb[k][j]) : 0u;
            const unsigned o  = ok ? (unsigned)od[k][j] : 1u;
            aaddr[idx] = A;
            ((unsigned*)&bop)[j] = (Bv << 2) | o;
            rk[idx] = atomicAdd(&hist[A >> 12], 1u);
        }
        ((uint4*)bo)[k * 512 + t] = bop;                   // pid = k*2048 + t*4 ..+3
    }
    __syncthreads();

    // ---- exclusive prefix scan of 64 band counts (one wave) -----------------
    if (t < NBAND) {
        const unsigned v = hist[t];
        unsigned s = v;
#pragma unroll
        for (int o = 1; o < 64; o <<= 1) {
            const unsigned u = __shfl_up(s, o, 64);
            if (t >= o) s += u;
        }
        pfx[t] = s - v;                                    // exclusive
    }
    __syncthreads();

    // ---- scatter A-tasks band-major ----------------------------------------
#pragma unroll
    for (int idx = 0; idx < 8; ++idx) {
        const unsigned pid = (unsigned)((idx >> 2) * 2048 + t * 4 + (idx & 3));
        taskA[pfx[aaddr[idx] >> 12] + rk[idx]] = (aaddr[idx] << 12) | pid;
    }
    __syncthreads();

    // ---- gather + fused loss: 8 points, 16 gathers in flight ---------------
    const uint4* tp = (const uint4*)taskA;
    const uint4 v0 = tp[t];
    const uint4 v1 = tp[512 + t];
    unsigned w[8] = { v0.x, v0.y, v0.z, v0.w, v1.x, v1.y, v1.z, v1.w };

    unsigned bv[8];
#pragma unroll
    for (int i = 0; i < 8; ++i) bv[i] = bo[w[i] & 4095u];  // random LDS, ~2-way

    unsigned qa[8], qb[8];
#pragma unroll
    for (int i = 0; i < 8; ++i) qa[i] = imb[w[i] >> 12];   // band-sorted: L1-warm
#pragma unroll
    for (int i = 0; i < 8; ++i) qb[i] = imb[bv[i] >> 2];   // unsorted B gathers

    float acc = 0.0f;
#pragma unroll
    for (int i = 0; i < 8; ++i) {
        const float d  = dec8(qa[i]) - dec8(qb[i]);
        const float g  = (float)(bv[i] & 3u) - 1.0f;       // -1, 0, +1
        const float m  = fabsf(g);
        const float tt = -g * d;
        const float sp = fmaxf(tt, 0.0f) + __logf(1.0f + __expf(-fabsf(tt)));
        acc += m * sp + (1.0f - m) * (d * d);              // branchless select
    }

    // ---- reduce: wave shuffle -> LDS -> one atomic per block ---------------
#pragma unroll
    for (int o = 32; o > 0; o >>= 1) acc += __shfl_down(acc, o, 64);
    const int lane = t & 63, wid = t >> 6;
    if (lane == 0) ws[wid] = acc;
    __syncthreads();
    if (t == 0) {
        float ssum = 0.0f;
#pragma unroll
        for (int w2 = 0; w2 < KG_THREADS / 64; ++w2) ssum += ws[w2];
        atomicAdd(out, ssum * (1.0f / (float)NTOT));
    }
}

extern "C" void kernel_launch(void* const* d_in, const int* in_sizes, int n_in,
                              void* d_out, int out_size, void* d_ws, size_t ws_size,
                              hipStream_t stream) {
    const float* img = (const float*)d_in[0];
    const int*   xA  = (const int*)d_in[1];
    const int*   yA  = (const int*)d_in[2];
    const int*   xB  = (const int*)d_in[3];
    const int*   yB  = (const int*)d_in[4];
    const int*   od  = (const int*)d_in[5];
    float* out = (float*)d_out;

    // ws: int8 image only (8 MB). No cursors, no records, no memset.
    unsigned* bimg_u32 = (unsigned*)d_ws;

    kConv<<<NBLK_CONV, 256, 0, stream>>>(img, bimg_u32, out);
    kG<<<NBLK_G, KG_THREADS, 0, stream>>>((const unsigned char*)bimg_u32,
                                          xA, yA, xB, yB, od, out);
}

// Round 8
// 142.575 us; speedup vs baseline: 1.0402x; 1.0402x over previous
//
#include <hip/hip_runtime.h>
#include <stdint.h>

// Problem constants: B=32, H=512, W=512, P=100000
#define W_        512
#define HWIMG     (512 * 512)
#define P_        100000
#define B_        32
#define NTOT      3200000
#define NBLK_CONV 1024
#define KG_THREADS 512
#define CHUNK     4096                 // points per gather block (512 thr * 8)
#define NCHUNK    25                   // 25*4096 = 102400 >= P_
#define NBLK_G    (B_ * NCHUNK)        // 800
#define NTASK     8192                 // 2 gathers per point
#define NBAND     64                   // 4 KB image bands (8 rows of int8)

typedef int   iv4 __attribute__((ext_vector_type(4)));
typedef float fv4 __attribute__((ext_vector_type(4)));

// ---- linear int8 quantization (R12-proven) ---------------------------------
__device__ __forceinline__ unsigned enc8(float z) {
    int q = __float2int_rn(fmaf(z, 32.0f, 128.0f));
    q = q < 0 ? 0 : (q > 255 ? 255 : q);
    return (unsigned)q;
}
__device__ __forceinline__ float dec8(unsigned q) {
    return fmaf((float)q, 0.03125f, -4.0f);
}

// ============ kernel 1: image fp32 -> int8 convert ==========================
// XCD-aligned batch mapping so each XCD's L2 keeps its 4 batches' int8 images
// (1 MB/XCD) dirty-resident for kernel 2's gathers (same mapping).
__global__ __launch_bounds__(256) void kConv(
    const float* __restrict__ img,
    unsigned* __restrict__ bimg_u32,
    float* __restrict__ out)
{
    const int t = threadIdx.x;
    if (blockIdx.x == 0 && t == 0) out[0] = 0.0f;
    const int b0    = blockIdx.x;
    const int batch = ((b0 & 7) << 2) | ((b0 >> 3) & 3);   // XCD-aligned
    const int inner = b0 >> 5;                             // 0..31
    const fv4* src = (const fv4*)img + (size_t)batch * 65536 + inner * 2048;
    unsigned*  dst = bimg_u32 + (size_t)batch * 65536 + inner * 2048;
#pragma unroll
    for (int ii = 0; ii < 8; ++ii) {
        const int idx = ii * 256 + t;
        const fv4 f = __builtin_nontemporal_load(src + idx);
        dst[idx] = enc8(f.x) | (enc8(f.y) << 8) | (enc8(f.z) << 16) | (enc8(f.w) << 24);
    }
}

// ============ kernel 2: band-sorted gather + loss ===========================
// Per block: 4096 points -> 8192 gather tasks (reuse per block concentrates:
// unique-64B-lines per block 43% of tasks -> 2.8M total L2 gather requests).
// Counting-sort tasks by 4 KB image band in LDS, gather band-ordered (reuse
// window L1-resident), ds_write result bytes by task id, conflict-free
// contiguous readback + branchless loss + reduce.  [R4: best measured 141.5]
__global__ __launch_bounds__(KG_THREADS) void kG(
    const unsigned char* __restrict__ bimg,
    const int* __restrict__ xA, const int* __restrict__ yA,
    const int* __restrict__ xB, const int* __restrict__ yB,
    const int* __restrict__ ordn,
    float* __restrict__ out)
{
    __shared__ unsigned tasks[NTASK];                  // 32 KB: (addr<<13)|taskid
    __shared__ unsigned char res[NTASK];               // 8 KB: gathered bytes
    __shared__ unsigned hist[NBAND];
    __shared__ unsigned pfx[NBAND];
    __shared__ float ws[KG_THREADS / 64];

    const int t     = threadIdx.x;
    const int lb    = blockIdx.x;                          // 0..799
    const int batch = ((lb & 7) << 2) | ((lb >> 3) & 3);   // XCD-aligned (matches kConv)
    const int base  = (lb >> 5) * CHUNK;                   // chunk 0..24
    const unsigned char* imb = bimg + (size_t)batch * HWIMG;

    if (t < NBAND) hist[t] = 0;
    __syncthreads();

    // ---- load indices (branchless), build tasks, LDS histogram -------------
    unsigned addr[16], rk[16];
    float    gtf[8];
    bool     okk[2];
#pragma unroll
    for (int k = 0; k < 2; ++k) {
        const int pl = base + k * 2048 + t * 4;
        const bool ok = pl < P_;                           // P_%4==0 -> whole iv4 valid
        okk[k] = ok;
        const int gi = batch * P_ + (ok ? pl : 0);
        const iv4 xa = __builtin_nontemporal_load((const iv4*)(xA + gi));
        const iv4 ya = __builtin_nontemporal_load((const iv4*)(yA + gi));
        const iv4 xb = __builtin_nontemporal_load((const iv4*)(xB + gi));
        const iv4 yb = __builtin_nontemporal_load((const iv4*)(yB + gi));
        const iv4 od = __builtin_nontemporal_load((const iv4*)(ordn + gi));
#pragma unroll
        for (int j = 0; j < 4; ++j) {
            const int i = k * 8 + j * 2;
            addr[i]     = ((unsigned)ya[j] << 9) | (unsigned)xa[j];
            addr[i + 1] = ((unsigned)yb[j] << 9) | (unsigned)xb[j];
            gtf[k * 4 + j] = (float)od[j] - 1.0f;          // -1, 0, +1
            rk[i]     = atomicAdd(&hist[addr[i]     >> 12], 1u);
            rk[i + 1] = atomicAdd(&hist[addr[i + 1] >> 12], 1u);
        }
    }
    __syncthreads();

    // ---- exclusive prefix scan of 64 band counts (one wave) -----------------
    if (t < NBAND) {
        const unsigned v = hist[t];
        unsigned s = v;
#pragma unroll
        for (int o = 1; o < 64; o <<= 1) {
            const unsigned u = __shfl_up(s, o, 64);
            if (t >= o) s += u;
        }
        pfx[t] = s - v;                                    // exclusive
    }
    __syncthreads();

    // ---- scatter tasks band-major ------------------------------------------
#pragma unroll
    for (int k = 0; k < 2; ++k) {
#pragma unroll
        for (int j = 0; j < 4; ++j) {
            const int i = k * 8 + j * 2;
            // taskid: point p = k*2048 + t*4 + j; A-slot 2p, B-slot 2p+1
            const unsigned p  = (unsigned)(k * 2048 + t * 4 + j);
            tasks[pfx[addr[i]     >> 12] + rk[i]]     = (addr[i]     << 13) | (p * 2u);
            tasks[pfx[addr[i + 1] >> 12] + rk[i + 1]] = (addr[i + 1] << 13) | (p * 2u + 1u);
        }
    }
    __syncthreads();

    // ---- band-ordered gathers: consecutive tasks = same 4 KB band -> L1 ----
#pragma unroll
    for (int it = 0; it < NTASK / KG_THREADS; ++it) {
        const unsigned v  = tasks[it * KG_THREADS + t];
        const unsigned q  = imb[v >> 13];
        res[v & 8191u] = (unsigned char)q;
    }
    __syncthreads();

    // ---- readback (contiguous 8 bytes per thread per k -> conflict-free) ---
    float acc = 0.0f;
#pragma unroll
    for (int k = 0; k < 2; ++k) {
        // bytes [ (k*2048 + t*4)*2 , +8 )  == res + k*4096 + t*8
        const unsigned char* rp = res + k * 4096 + t * 8;
        float s = 0.0f;
#pragma unroll
        for (int j = 0; j < 4; ++j) {
            const float d  = dec8((unsigned)rp[j * 2]) - dec8((unsigned)rp[j * 2 + 1]);
            const float g  = gtf[k * 4 + j];
            const float m  = fabsf(g);
            const float tt = -g * d;
            const float sp = fmaxf(tt, 0.0f) + __logf(1.0f + __expf(-fabsf(tt)));
            s += m * sp + (1.0f - m) * (d * d);
        }
        acc += okk[k] ? s : 0.0f;
    }

    // ---- reduce: wave shuffle -> LDS -> one atomic per block ---------------
#pragma unroll
    for (int o = 32; o > 0; o >>= 1) acc += __shfl_down(acc, o, 64);
    const int lane = t & 63, wid = t >> 6;
    if (lane == 0) ws[wid] = acc;
    __syncthreads();
    if (t == 0) {
        float ssum = 0.0f;
#pragma unroll
        for (int w = 0; w < KG_THREADS / 64; ++w) ssum += ws[w];
        atomicAdd(out, ssum * (1.0f / (float)NTOT));
    }
}

extern "C" void kernel_launch(void* const* d_in, const int* in_sizes, int n_in,
                              void* d_out, int out_size, void* d_ws, size_t ws_size,
                              hipStream_t stream) {
    const float* img = (const float*)d_in[0];
    const int*   xA  = (const int*)d_in[1];
    const int*   yA  = (const int*)d_in[2];
    const int*   xB  = (const int*)d_in[3];
    const int*   yB  = (const int*)d_in[4];
    const int*   od  = (const int*)d_in[5];
    float* out = (float*)d_out;

    // ws: int8 image only (8 MB). No cursors, no records, no memset.
    unsigned* bimg_u32 = (unsigned*)d_ws;

    kConv<<<NBLK_CONV, 256, 0, stream>>>(img, bimg_u32, out);
    kG<<<NBLK_G, KG_THREADS, 0, stream>>>((const unsigned char*)bimg_u32,
                                          xA, yA, xB, yB, od, out);
}